// Round 1
// baseline (131.288 us; speedup 1.0000x reference)
//
#include <hip/hip_runtime.h>

#define KS 3
#define N9 9
#define TPX 16          // pixels per block (contiguous j within one row)
#define CIN 64
#define COUT 64
#define HH 64
#define WW 64
#define BB 8
#define HP 66           // padded H/W
#define KTOT (CIN * N9) // 576

// ---- prep: transpose weight (co, ci, 3, 3) -> Wt[k=ci*9+n][co] ----
__global__ __launch_bounds__(256) void wt_transpose(const float* __restrict__ w,
                                                    float* __restrict__ wt) {
    int idx = blockIdx.x * 256 + threadIdx.x;   // idx = co*576 + k
    if (idx < COUT * KTOT) {
        int co = idx / KTOT;
        int k  = idx - co * KTOT;
        wt[k * COUT + co] = w[idx];
    }
}

// ---- main kernel: one block = 16 output pixels, all 64 c_out ----
__global__ __launch_bounds__(256) void deform_main(
    const float* __restrict__ x,     // (8, 64, 64, 64)
    const float* __restrict__ off,   // (8, 18, 64, 64)
    const float* __restrict__ wt,    // (576, 64)
    float* __restrict__ out) {       // (8, 64, 64, 64)

    __shared__ float4 s_w4[N9][TPX];     // 4 bilinear weights per (n, px)
    __shared__ int4   s_i4[N9][TPX];     // 4 gather indices (plane-relative), 0 if dead
    __shared__ float  S[KTOT][TPX];      // sampled values

    const int t    = threadIdx.x;
    const int pix0 = blockIdx.x * TPX;
    const int b    = pix0 >> 12;
    const int i    = (pix0 >> 6) & 63;
    const int j0   = pix0 & 63;

    // ---- phase 0: sampling geometry (144 threads) ----
    if (t < N9 * TPX) {
        const int n  = t >> 4;
        const int px = t & 15;
        const int j  = j0 + px;
        const float offx = off[(((b * 18) + 2 * n) * HH + i) * WW + j];
        const float offy = off[(((b * 18) + 2 * n + 1) * HH + i) * WW + j];
        // p = p0 + pn + offset   (padded coords; p0x=i+1, pnx=n/3-1)
        const float pxf = (float)(i + n / 3) + offx;
        const float pyf = (float)(j + n % 3) + offy;
        const float fpx = floorf(pxf);
        const float fpy = floorf(pyf);
        const float qltx = fminf(fmaxf(fpx, 0.f), 65.f);
        const float qlty = fminf(fmaxf(fpy, 0.f), 65.f);
        const float qrbx = fminf(fmaxf(fpx + 1.f, 0.f), 65.f);
        const float qrby = fminf(fmaxf(fpy + 1.f, 0.f), 65.f);
        // mask: snap out-of-range p to floor(p)
        const bool mx = (pxf < 1.f) || (pxf > 64.f);
        const bool my = (pyf < 1.f) || (pyf > 64.f);
        const float Px = fminf(fmaxf(mx ? fpx : pxf, 0.f), 65.f);
        const float Py = fminf(fmaxf(my ? fpy : pyf, 0.f), 65.f);
        // bilinear weights exactly as reference
        float glt = (1.f + (qltx - Px)) * (1.f + (qlty - Py));
        float grb = (1.f - (qrbx - Px)) * (1.f - (qrby - Py));
        float glb = (1.f + (qltx - Px)) * (1.f - (qrby - Py));
        float grt = (1.f - (qrbx - Px)) * (1.f + (qlty - Py));
        const int ltx = (int)qltx, lty = (int)qlty;
        const int rbx = (int)qrbx, rby = (int)qrby;
        // corner -> (row, col) in padded coords; zero-pad ring => value 0
        int i0, i1, i2, i3;
        {
            bool vx0 = (ltx >= 1) & (ltx <= 64);
            bool vx1 = (rbx >= 1) & (rbx <= 64);
            bool vy0 = (lty >= 1) & (lty <= 64);
            bool vy1 = (rby >= 1) & (rby <= 64);
            bool v_lt = vx0 & vy0, v_rb = vx1 & vy1, v_lb = vx0 & vy1, v_rt = vx1 & vy0;
            i0 = v_lt ? (ltx - 1) * WW + (lty - 1) : 0;  if (!v_lt) glt = 0.f;
            i1 = v_rb ? (rbx - 1) * WW + (rby - 1) : 0;  if (!v_rb) grb = 0.f;
            i2 = v_lb ? (ltx - 1) * WW + (rby - 1) : 0;  if (!v_lb) glb = 0.f;
            i3 = v_rt ? (rbx - 1) * WW + (lty - 1) : 0;  if (!v_rt) grt = 0.f;
        }
        s_w4[n][px] = make_float4(glt, grb, glb, grt);
        s_i4[n][px] = make_int4(i0, i1, i2, i3);
    }
    __syncthreads();

    // ---- phase 1: gather + blend 576 x 16 samples into LDS ----
    const float* xb = x + b * (CIN * HH * WW);
    #pragma unroll 4
    for (int it = 0; it < (CIN * N9 * TPX) / 256; ++it) {   // 36 iters
        const int task = it * 256 + t;
        const int ci   = task / (N9 * TPX);
        const int rem  = task - ci * (N9 * TPX);
        const int n    = rem >> 4;
        const int px   = rem & 15;
        const float* xp = xb + ci * (HH * WW);
        const float4 wv = s_w4[n][px];
        const int4   iv = s_i4[n][px];
        float v = wv.x * xp[iv.x] + wv.y * xp[iv.y] + wv.z * xp[iv.z] + wv.w * xp[iv.w];
        S[ci * N9 + n][px] = v;
    }
    __syncthreads();

    // ---- phase 2: out[co, px] = sum_k Wt[k][co] * S[k][px] ----
    const int co = t >> 2;
    const int pq = (t & 3) * 4;
    float a0 = 0.f, a1 = 0.f, a2 = 0.f, a3 = 0.f;
    const float* wtp = wt + co;
    #pragma unroll 4
    for (int k = 0; k < KTOT; ++k) {
        const float wv = wtp[k * COUT];
        const float4 s = *(const float4*)&S[k][pq];
        a0 += wv * s.x; a1 += wv * s.y; a2 += wv * s.z; a3 += wv * s.w;
    }
    float* op = out + (((b * COUT) + co) * HH + i) * WW + j0 + pq;
    op[0] = a0; op[1] = a1; op[2] = a2; op[3] = a3;
}

extern "C" void kernel_launch(void* const* d_in, const int* in_sizes, int n_in,
                              void* d_out, int out_size, void* d_ws, size_t ws_size,
                              hipStream_t stream) {
    const float* x   = (const float*)d_in[0];
    const float* off = (const float*)d_in[1];
    const float* w   = (const float*)d_in[2];
    float* out = (float*)d_out;
    float* wtr = (float*)d_ws;   // 576*64 floats = 147456 B

    hipLaunchKernelGGL(wt_transpose, dim3((COUT * KTOT + 255) / 256), dim3(256), 0, stream,
                       w, wtr);
    hipLaunchKernelGGL(deform_main, dim3(BB * HH * WW / TPX), dim3(256), 0, stream,
                       x, off, wtr, out);
}

// Round 2
// 69.779 us; speedup vs baseline: 1.8815x; 1.8815x over previous
//
#include <hip/hip_runtime.h>
#include <hip/hip_bf16.h>

#define N9 9
#define TPX 16          // pixels per block (contiguous j within one row)
#define CIN 64
#define COUT 64
#define HH 64
#define WW 64
#define BB 8
#define KTOT 576        // 64 ci * 9 points
#define SROW 584        // padded LDS row stride in shorts (1168 B = 73*16)

typedef short bf16x8 __attribute__((ext_vector_type(8)));
typedef float f32x4 __attribute__((ext_vector_type(4)));

// ---- prep: cast weight (co, ci, 3, 3) fp32 -> bf16, same layout [co][k] ----
__global__ __launch_bounds__(256) void wt_bf16_conv(const float* __restrict__ w,
                                                    short* __restrict__ wt) {
    int idx = blockIdx.x * 256 + threadIdx.x;
    if (idx < COUT * KTOT) {
        __hip_bfloat16 h = __float2bfloat16(w[idx]);
        wt[idx] = *reinterpret_cast<short*>(&h);
    }
}

// ---- main kernel: one block = 16 output pixels, all 64 c_out ----
__global__ __launch_bounds__(256) void deform_main(
    const float* __restrict__ x,     // (8, 64, 64, 64)
    const float* __restrict__ off,   // (8, 18, 64, 64)
    const short* __restrict__ wtb,   // (64, 576) bf16
    float* __restrict__ out) {       // (8, 64, 64, 64)

    __shared__ int    s_base[N9][TPX];   // clamped 2x2 patch base (plane-relative)
    __shared__ float4 s_g[N9][TPX];      // weights for (r,c),(r,c+1),(r+1,c),(r+1,c+1)
    __attribute__((aligned(16))) __shared__ short S[TPX][SROW];  // samples, bf16

    const int t    = threadIdx.x;
    const int pix0 = blockIdx.x * TPX;
    const int b    = pix0 >> 12;
    const int i    = (pix0 >> 6) & 63;
    const int j0   = pix0 & 63;

    // ---- phase 0: sampling geometry (144 threads) ----
    if (t < N9 * TPX) {
        const int n  = t >> 4;
        const int px = t & 15;
        const int j  = j0 + px;
        const float offx = off[(((b * 18) + 2 * n) * HH + i) * WW + j];
        const float offy = off[(((b * 18) + 2 * n + 1) * HH + i) * WW + j];
        // p in padded coords: p0 + pn + offset
        const float pxf = (float)(i + n / 3) + offx;
        const float pyf = (float)(j + n % 3) + offy;
        const float fpx = floorf(pxf);
        const float fpy = floorf(pyf);
        const float qltx = fminf(fmaxf(fpx, 0.f), 65.f);
        const float qlty = fminf(fmaxf(fpy, 0.f), 65.f);
        const float qrbx = fminf(fmaxf(fpx + 1.f, 0.f), 65.f);
        const float qrby = fminf(fmaxf(fpy + 1.f, 0.f), 65.f);
        const bool mx = (pxf < 1.f) || (pxf > 64.f);
        const bool my = (pyf < 1.f) || (pyf > 64.f);
        const float Px = fminf(fmaxf(mx ? fpx : pxf, 0.f), 65.f);
        const float Py = fminf(fmaxf(my ? fpy : pyf, 0.f), 65.f);
        // separable bilinear factors; per-corner product == reference g_*
        float ul = 1.f + (qltx - Px);
        float ur = 1.f - (qrbx - Px);
        float wl = 1.f + (qlty - Py);
        float wr = 1.f - (qrby - Py);
        const int ltx = (int)qltx, lty = (int)qlty;
        const int rbx = (int)qrbx, rby = (int)qrby;
        // zero-pad ring => corner dead iff its row or col lands in the ring
        if (ltx < 1 || ltx > 64) ul = 0.f;
        if (rbx < 1 || rbx > 64) ur = 0.f;
        if (lty < 1 || lty > 64) wl = 0.f;
        if (rby < 1 || rby > 64) wr = 0.f;
        // shifted 2x2 patch: rows rp,rp+1 / cols cp,cp+1 (always in-plane);
        // weight swizzle proves: whenever a needed row/col isn't in the patch,
        // its factor is already 0 (clip cases are masked above).
        const int r = ltx - 1, c = lty - 1;
        const int rp = min(max(r, 0), 62), cp = min(max(c, 0), 62);
        const float u0 = (rp == r ? ul : 0.f) + (rp == rbx - 1 ? ur : 0.f);
        const float u1 = (rp + 1 == r ? ul : 0.f) + (rp + 1 == rbx - 1 ? ur : 0.f);
        const float w0 = (cp == c ? wl : 0.f) + (cp == rby - 1 ? wr : 0.f);
        const float w1 = (cp + 1 == c ? wl : 0.f) + (cp + 1 == rby - 1 ? wr : 0.f);
        s_base[n][px] = rp * WW + cp;
        s_g[n][px] = make_float4(u0 * w0, u0 * w1, u1 * w0, u1 * w1);
    }
    __syncthreads();

    // ---- phase 1: gather 2x2 patches, blend, store bf16 to S[px][k] ----
    const float* xb = x + b * (CIN * HH * WW);
    #pragma unroll 4
    for (int it = 0; it < (CIN * N9 * TPX) / 256; ++it) {   // 36 iters
        const int task = it * 256 + t;
        const int ci   = task / (N9 * TPX);
        const int rem  = task - ci * (N9 * TPX);
        const int n    = rem >> 4;
        const int px   = rem & 15;
        const float* xp = xb + (ci << 12);
        const int   bse = s_base[n][px];
        const float4 g  = s_g[n][px];
        float y[4];
        __builtin_memcpy(y, xp + bse, 8);            // (r, c..c+1)
        __builtin_memcpy(y + 2, xp + bse + WW, 8);   // (r+1, c..c+1)
        const float v = g.x * y[0] + g.y * y[1] + g.z * y[2] + g.w * y[3];
        __hip_bfloat16 h = __float2bfloat16(v);
        S[px][ci * N9 + n] = *reinterpret_cast<short*>(&h);
    }
    __syncthreads();

    // ---- phase 2: MFMA GEMM  out[co,px] = sum_k wt[co][k] * S[px][k] ----
    const int lane = t & 63;
    const int wave = t >> 6;
    const int co_base = wave * 16;
    const int lr = lane & 15;        // A row (co) / B col (px) / D col (px)
    const int kq = lane >> 4;        // k-octet selector
    f32x4 acc = {0.f, 0.f, 0.f, 0.f};
    const short* arow = wtb + (co_base + lr) * KTOT + kq * 8;
    const short* brow = &S[lr][kq * 8];
    #pragma unroll
    for (int kk = 0; kk < KTOT / 32; ++kk) {        // 18 MFMAs
        bf16x8 a = *reinterpret_cast<const bf16x8*>(arow + kk * 32);
        bf16x8 bf = *reinterpret_cast<const bf16x8*>(brow + kk * 32);
        acc = __builtin_amdgcn_mfma_f32_16x16x32_bf16(a, bf, acc, 0, 0, 0);
    }
    #pragma unroll
    for (int v = 0; v < 4; ++v) {
        const int co = co_base + kq * 4 + v;        // D row = (lane>>4)*4 + v
        out[((b * COUT + co) * HH + i) * WW + j0 + lr] = acc[v];
    }
}

extern "C" void kernel_launch(void* const* d_in, const int* in_sizes, int n_in,
                              void* d_out, int out_size, void* d_ws, size_t ws_size,
                              hipStream_t stream) {
    const float* x   = (const float*)d_in[0];
    const float* off = (const float*)d_in[1];
    const float* w   = (const float*)d_in[2];
    float* out = (float*)d_out;
    short* wtb = (short*)d_ws;   // 64*576 bf16 = 73728 B

    hipLaunchKernelGGL(wt_bf16_conv, dim3((COUT * KTOT + 255) / 256), dim3(256), 0, stream,
                       w, wtb);
    hipLaunchKernelGGL(deform_main, dim3(BB * HH * WW / TPX), dim3(256), 0, stream,
                       x, off, wtb, out);
}

// Round 3
// 50.530 us; speedup vs baseline: 2.5982x; 1.3809x over previous
//
#include <hip/hip_runtime.h>
#include <hip/hip_bf16.h>

#define N9 9
#define TPX 16          // pixels per block (contiguous j within one row)
#define CIN 64
#define COUT 64
#define HH 64
#define WW 64
#define BB 8
#define KTOT 576        // 9 points * 64 ci, k = n*64 + ci
#define SROW 584        // padded LDS row stride in shorts (1168 B)

typedef short bf16x8 __attribute__((ext_vector_type(8)));
typedef float f32x4 __attribute__((ext_vector_type(4)));

// ---- prep A: weight (co, ci, 3, 3) fp32 -> bf16, permuted to [co][n*64+ci] ----
__global__ __launch_bounds__(256) void wt_prep(const float* __restrict__ w,
                                               short* __restrict__ wt) {
    int idx = blockIdx.x * 256 + threadIdx.x;    // co*576 + ci*9 + n
    if (idx < COUT * KTOT) {
        int co = idx / KTOT;
        int r  = idx - co * KTOT;
        int ci = r / N9;
        int n  = r - ci * N9;
        __hip_bfloat16 h = __float2bfloat16(w[idx]);
        wt[co * KTOT + n * CIN + ci] = *reinterpret_cast<short*>(&h);
    }
}

// ---- prep B: x NCHW -> NHWC  xt[b][h][w][ci] ----
__global__ __launch_bounds__(256) void x_transpose(const float* __restrict__ x,
                                                   float* __restrict__ xt) {
    __shared__ float tile[64][65];
    const int bh = blockIdx.x;                    // b*64 + h
    const int b = bh >> 6, h = bh & 63;
    const int t = threadIdx.x;
    const int r0 = t >> 6;                        // 0..3
    const int c  = t & 63;
    const float* xp = x + ((b * CIN) * HH + h) * WW;
    #pragma unroll
    for (int s = 0; s < 16; ++s) {
        const int ci = s * 4 + r0;
        tile[ci][c] = xp[ci * (HH * WW) + c];     // coalesced in w
    }
    __syncthreads();
    float* xo = xt + (b * HH + h) * (WW * CIN);
    #pragma unroll
    for (int s = 0; s < 16; ++s) {
        const int w = s * 4 + r0;
        xo[w * CIN + c] = tile[c][w];             // coalesced in ci
    }
}

// ---- main kernel: one block = 16 output pixels, all 64 c_out ----
__global__ __launch_bounds__(256) void deform_main(
    const float* __restrict__ xt,    // (8, 64, 64, 64) NHWC
    const float* __restrict__ off,   // (8, 18, 64, 64)
    const short* __restrict__ wtb,   // (64, 576) bf16, k = n*64+ci
    float* __restrict__ out) {       // (8, 64, 64, 64)

    __shared__ int    s_base[N9][TPX];   // NHWC element offset of 2x2 patch base
    __shared__ float4 s_g[N9][TPX];      // weights (r,c),(r,c+1),(r+1,c),(r+1,c+1)
    __attribute__((aligned(16))) __shared__ short S[TPX][SROW];

    const int t    = threadIdx.x;
    const int lane = t & 63;
    const int wave = t >> 6;

    // XCD swizzle: each XCD (g&7) owns one full batch -> L2-resident working set
    const int logical = (blockIdx.x & 7) * 256 + (blockIdx.x >> 3);
    const int pix0 = logical * TPX;
    const int b    = pix0 >> 12;
    const int i    = (pix0 >> 6) & 63;
    const int j0   = pix0 & 63;

    // ---- prefetch A fragments (weights) into registers, overlap with gather ----
    const int lr = lane & 15;        // A row (co) / B col (px)
    const int kq = lane >> 4;        // k-octet selector
    const short* arow = wtb + (wave * 16 + lr) * KTOT + kq * 8;
    bf16x8 afr[18];
    #pragma unroll
    for (int kk = 0; kk < 18; ++kk)
        afr[kk] = *reinterpret_cast<const bf16x8*>(arow + kk * 32);

    // ---- phase 0: sampling geometry (144 threads) ----
    if (t < N9 * TPX) {
        const int n  = t >> 4;
        const int px = t & 15;
        const int j  = j0 + px;
        const float offx = off[(((b * 18) + 2 * n) * HH + i) * WW + j];
        const float offy = off[(((b * 18) + 2 * n + 1) * HH + i) * WW + j];
        const float pxf = (float)(i + n / 3) + offx;
        const float pyf = (float)(j + n % 3) + offy;
        const float fpx = floorf(pxf);
        const float fpy = floorf(pyf);
        const float qltx = fminf(fmaxf(fpx, 0.f), 65.f);
        const float qlty = fminf(fmaxf(fpy, 0.f), 65.f);
        const float qrbx = fminf(fmaxf(fpx + 1.f, 0.f), 65.f);
        const float qrby = fminf(fmaxf(fpy + 1.f, 0.f), 65.f);
        const bool mx = (pxf < 1.f) || (pxf > 64.f);
        const bool my = (pyf < 1.f) || (pyf > 64.f);
        const float Px = fminf(fmaxf(mx ? fpx : pxf, 0.f), 65.f);
        const float Py = fminf(fmaxf(my ? fpy : pyf, 0.f), 65.f);
        float ul = 1.f + (qltx - Px);
        float ur = 1.f - (qrbx - Px);
        float wl = 1.f + (qlty - Py);
        float wr = 1.f - (qrby - Py);
        const int ltx = (int)qltx, lty = (int)qlty;
        const int rbx = (int)qrbx, rby = (int)qrby;
        if (ltx < 1 || ltx > 64) ul = 0.f;
        if (rbx < 1 || rbx > 64) ur = 0.f;
        if (lty < 1 || lty > 64) wl = 0.f;
        if (rby < 1 || rby > 64) wr = 0.f;
        const int r = ltx - 1, c = lty - 1;
        const int rp = min(max(r, 0), 62), cp = min(max(c, 0), 62);
        const float u0 = (rp == r ? ul : 0.f) + (rp == rbx - 1 ? ur : 0.f);
        const float u1 = (rp + 1 == r ? ul : 0.f) + (rp + 1 == rbx - 1 ? ur : 0.f);
        const float w0 = (cp == c ? wl : 0.f) + (cp == rby - 1 ? wr : 0.f);
        const float w1 = (cp + 1 == c ? wl : 0.f) + (cp + 1 == rby - 1 ? wr : 0.f);
        s_base[n][px] = (rp * WW + cp) * CIN;
        s_g[n][px] = make_float4(u0 * w0, u0 * w1, u1 * w0, u1 * w1);
    }
    __syncthreads();

    // ---- phase 1: coalesced gather (lane = ci), blend, store bf16 ----
    const float* xb = xt + b * (HH * WW * CIN);
    #pragma unroll 4
    for (int it = 0; it < 36; ++it) {            // wave-uniform (n, px)
        const int q  = wave * 36 + it;
        const int n  = q >> 4;
        const int px = q & 15;
        const int bse = s_base[n][px];
        const float4 g = s_g[n][px];
        const float y00 = xb[bse + lane];
        const float y01 = xb[bse + CIN + lane];
        const float y10 = xb[bse + WW * CIN + lane];
        const float y11 = xb[bse + WW * CIN + CIN + lane];
        const float v = g.x * y00 + g.y * y01 + g.z * y10 + g.w * y11;
        __hip_bfloat16 h = __float2bfloat16(v);
        S[px][n * CIN + lane] = *reinterpret_cast<short*>(&h);
    }
    __syncthreads();

    // ---- phase 2: MFMA GEMM  out[co,px] = sum_k wt[co][k] * S[px][k] ----
    f32x4 acc = {0.f, 0.f, 0.f, 0.f};
    const short* brow = &S[lr][kq * 8];
    #pragma unroll
    for (int kk = 0; kk < 18; ++kk) {
        bf16x8 bf = *reinterpret_cast<const bf16x8*>(brow + kk * 32);
        acc = __builtin_amdgcn_mfma_f32_16x16x32_bf16(afr[kk], bf, acc, 0, 0, 0);
    }
    #pragma unroll
    for (int v = 0; v < 4; ++v) {
        const int co = wave * 16 + kq * 4 + v;   // D row = (lane>>4)*4 + v
        out[((b * COUT + co) * HH + i) * WW + j0 + lr] = acc[v];
    }
}

extern "C" void kernel_launch(void* const* d_in, const int* in_sizes, int n_in,
                              void* d_out, int out_size, void* d_ws, size_t ws_size,
                              hipStream_t stream) {
    const float* x   = (const float*)d_in[0];
    const float* off = (const float*)d_in[1];
    const float* w   = (const float*)d_in[2];
    float* out = (float*)d_out;
    short* wtb = (short*)d_ws;                       // 73728 B
    float* xt  = (float*)((char*)d_ws + 131072);     // 8.4 MB NHWC copy

    hipLaunchKernelGGL(wt_prep, dim3((COUT * KTOT + 255) / 256), dim3(256), 0, stream,
                       w, wtb);
    hipLaunchKernelGGL(x_transpose, dim3(BB * HH), dim3(256), 0, stream, x, xt);
    hipLaunchKernelGGL(deform_main, dim3(BB * HH * WW / TPX), dim3(256), 0, stream,
                       xt, off, wtb, out);
}